// Round 12
// baseline (295.531 us; speedup 1.0000x reference)
//
#include <hip/hip_runtime.h>
#include <hip/hip_fp16.h>

#define HDIM 256
#define MS 16
#define LDAK 264   // 256 + 8 halves pad; measured-balanced for b128 reads & b64 writes
#define CSTRIDE (MS * LDAK * 2)          // 8448 B per channel block
#define ABUF_HALVES (7 * MS * LDAK)      // 29568 halves = 59136 B per buffer
#define SMEM_BYTES (2 * ABUF_HALVES * 2) // 118272 B (ping-pong)

typedef _Float16 half8 __attribute__((ext_vector_type(8)));
typedef _Float16 half4 __attribute__((ext_vector_type(4)));
typedef _Float16 half2v __attribute__((ext_vector_type(2)));
typedef __fp16  fp16x8 __attribute__((ext_vector_type(8)));
typedef float f32x4 __attribute__((ext_vector_type(4)));

__device__ __forceinline__ float fast_tanh(float x) {
    // tanh(x) = 1 - 2/(e^{2x}+1); v_exp-based, graceful at +-inf
    float e = __expf(2.0f * x);
    return 1.0f - 2.0f * __builtin_amdgcn_rcpf(e + 1.0f);
}

__device__ __forceinline__ half4 cvt4(float a, float b, float c, float d) {
    half2v lo = __builtin_bit_cast(half2v, __builtin_amdgcn_cvt_pkrtz(a, b));
    half2v hi = __builtin_bit_cast(half2v, __builtin_amdgcn_cvt_pkrtz(c, d));
    half4 r; r[0] = lo[0]; r[1] = lo[1]; r[2] = hi[0]; r[3] = hi[1];
    return r;
}

// Pack W1,W2,W3 (fp32 [256][256]) into f16 frag layout Wp[g*8192 + frag], g = flat
// K-step l*8+s. Block 96 packs Wout (256 f32) to f16 at Wp + 196608.
__global__ __launch_bounds__(256) void pack_weights(const float* __restrict__ W1,
                                                    const float* __restrict__ W2,
                                                    const float* __restrict__ W3,
                                                    const float* __restrict__ Wout,
                                                    _Float16* __restrict__ out) {
    if (blockIdx.x == 96) {
        int t = threadIdx.x;
        if (t < HDIM) out[3 * 65536 + t] = (_Float16)Wout[t];
        return;
    }
    int tid = blockIdx.x * 256 + threadIdx.x;  // 0..24575
    int l = tid >> 13;
    int idx = tid & 8191;   // kg*256 + n
    int kg = idx >> 8;      // k-group of 8
    int n = idx & 255;
    const float* W = (l == 0) ? W1 : (l == 1) ? W2 : W3;
    half8 v;
    #pragma unroll
    for (int j = 0; j < 8; ++j) v[j] = (_Float16)W[(kg * 8 + j) * 256 + n];
    *(half8*)(out + l * 65536 + kg * 2048 + n * 8) = v;
}

// One 16-sample tile per block; ping-pong Abuf kills the post-K barrier:
// layer l reads buf[l&1], elem writes buf[(l+1)&1] -> K->elem needs no sync.
// 1 block/CU, 1 wave/SIMD: full 512-VGPR budget for a deep explicit pipeline.
__global__ __launch_bounds__(256, 1)
void pinn_fused(const float* __restrict__ x,
                const float* __restrict__ W0,
                const float* __restrict__ b0,
                const float* __restrict__ b1,
                const float* __restrict__ b2,
                const float* __restrict__ b3,
                const _Float16* __restrict__ Wq,   // f16 Wout
                const float* __restrict__ bout,
                const _Float16* __restrict__ Wp,
                float* __restrict__ out) {
    extern __shared__ __align__(16) _Float16 smem[];
    _Float16* const bufA = smem;                    // layers 0,2 read; 1 writes
    _Float16* const bufB = smem + ABUF_HALVES;      // layer 0,2 write; 1 reads

    const int tid  = threadIdx.x;
    const int lane = tid & 63;
    const int wid  = tid >> 6;        // wave 0..3 -> n-strip base wid*64
    const int qd   = lane >> 4;
    const int n15  = lane & 15;
    const int base = blockIdx.x * MS;
    const int nw   = wid * 64 + n15;

    // Linear W addressing: frag(g,t) at Wp + g*8192 + voff0 + t*128 (halves).
    const int voff0 = (qd * 256 + nw) * 8;

    // 3-deep W pipeline over flat step g; g=0,1 issued before layer-0 math.
    half8 wf[3][4];
    #pragma unroll
    for (int t = 0; t < 4; ++t)
        wf[0][t] = *(const half8*)(Wp + 0 * 8192 + voff0 + t * 128);
    #pragma unroll
    for (int t = 0; t < 4; ++t)
        wf[1][t] = *(const half8*)(Wp + 1 * 8192 + voff0 + t * 128);

    // ---------------- layer 0: 3 -> 256, jets analytic -> bufA ----------------
    {
        const int m  = tid & 15;
        const int nb = (tid >> 4) * 16;   // 16 consecutive n per thread, 2 chunks
        const float x0 = x[(base + m) * 3 + 0];
        const float x1 = x[(base + m) * 3 + 1];
        const float x2 = x[(base + m) * 3 + 2];
        #pragma unroll
        for (int ch = 0; ch < 2; ++ch) {
            const int n0 = nb + ch * 8;
            f32x4 w0v[2], w1v[2], w2v[2], bv[2];
            w0v[0] = *(const f32x4*)(W0 + n0);            w0v[1] = *(const f32x4*)(W0 + n0 + 4);
            w1v[0] = *(const f32x4*)(W0 + HDIM + n0);     w1v[1] = *(const f32x4*)(W0 + HDIM + n0 + 4);
            w2v[0] = *(const f32x4*)(W0 + 2 * HDIM + n0); w2v[1] = *(const f32x4*)(W0 + 2 * HDIM + n0 + 4);
            bv[0]  = *(const f32x4*)(b0 + n0);            bv[1]  = *(const f32x4*)(b0 + n0 + 4);
            half8 h[7];
            #pragma unroll
            for (int r = 0; r < 8; ++r) {
                const float w0 = w0v[r >> 2][r & 3];
                const float w1 = w1v[r >> 2][r & 3];
                const float w2 = w2v[r >> 2][r & 3];
                float z  = x0 * w0 + x1 * w1 + x2 * w2 + bv[r >> 2][r & 3];
                float tv = fast_tanh(z);
                float dd = 1.f - tv * tv;
                float c2 = -2.f * tv * dd;
                h[0][r] = (_Float16)tv;
                h[1][r] = (_Float16)(dd * w0);
                h[2][r] = (_Float16)(dd * w1);
                h[3][r] = (_Float16)(dd * w2);
                h[4][r] = (_Float16)(c2 * w0 * w0);
                h[5][r] = (_Float16)(c2 * w1 * w1);
                h[6][r] = (_Float16)(c2 * w2 * w2);
            }
            #pragma unroll
            for (int c = 0; c < 7; ++c)
                *(half8*)&bufA[(c * MS + m) * LDAK + n0] = h[c];
        }
    }
    __syncthreads();

    // ---------------- layers 1..3: transposed MFMA, ping-pong buffers ----------------
    const int abase = (n15 * LDAK + qd * 8) * 2;                 // read base (bytes)
    const int sbase = (n15 * LDAK + wid * 64 + qd * 4) * 2;      // write base (bytes)

    #pragma unroll
    for (int l = 0; l < 3; ++l) {
        const float* bb = (l == 0) ? b1 : (l == 1) ? b2 : b3;
        const char* Ab = (const char*)((l & 1) ? bufB : bufA);   // read buffer
        char* Sb = (char*)((l & 1) ? bufA : bufB);               // write buffer

        f32x4 acc[7][4];
        #pragma unroll
        for (int c = 0; c < 7; ++c)
            #pragma unroll
            for (int t = 0; t < 4; ++t) acc[c][t] = (f32x4){0.f, 0.f, 0.f, 0.f};

        // explicit af double-buffer (register budget is ample at 1 wave/SIMD)
        half8 af[2][7];
        #pragma unroll
        for (int c = 0; c < 7; ++c)
            af[0][c] = *(const half8*)(Ab + abase + c * CSTRIDE);

        #pragma unroll
        for (int s = 0; s < 8; ++s) {
            const int g = l * 8 + s;
            if (g + 2 < 24) {   // prefetch step g+2's W frags (linear address)
                #pragma unroll
                for (int t = 0; t < 4; ++t)
                    wf[(g + 2) % 3][t] =
                        *(const half8*)(Wp + (g + 2) * 8192 + voff0 + t * 128);
            }
            if (s < 7) {        // prefetch step s+1's A frags
                #pragma unroll
                for (int c = 0; c < 7; ++c)
                    af[(s + 1) & 1][c] =
                        *(const half8*)(Ab + abase + c * CSTRIDE + (s + 1) * 64);
            }
            #pragma unroll
            for (int c = 0; c < 7; ++c)
                #pragma unroll
                for (int t = 0; t < 4; ++t)
                    acc[c][t] = __builtin_amdgcn_mfma_f32_16x16x32_f16(wf[g % 3][t], af[s & 1][c], acc[c][t], 0, 0, 0);
        }
        // NO barrier: elem writes go to the other buffer; readers untouched.

        // lane holds Z[m = n15][n = wid*64 + t*16 + qd*4 + r], r=0..3
        #pragma unroll
        for (int t = 0; t < 4; ++t) {
            const int ncol = wid * 64 + t * 16 + qd * 4;
            f32x4 bv = *(const f32x4*)(bb + ncol);
            float tv[4], gj[3][4], sj[3][4];
            #pragma unroll
            for (int r = 0; r < 4; ++r) {
                float zv = acc[0][t][r] + bv[r];
                tv[r] = fast_tanh(zv);
                float dd = 1.f - tv[r] * tv[r];
                float c2 = -2.f * tv[r] * dd;
                #pragma unroll
                for (int i = 0; i < 3; ++i) {
                    float zg = acc[1 + i][t][r];
                    float zs = acc[4 + i][t][r];
                    gj[i][r] = dd * zg;
                    sj[i][r] = dd * zs + c2 * zg * zg;
                }
            }
            *(half4*)(Sb + sbase + 0 * CSTRIDE + t * 32) = cvt4(tv[0], tv[1], tv[2], tv[3]);
            #pragma unroll
            for (int i = 0; i < 3; ++i) {
                *(half4*)(Sb + sbase + (1 + i) * CSTRIDE + t * 32) =
                    cvt4(gj[i][0], gj[i][1], gj[i][2], gj[i][3]);
                *(half4*)(Sb + sbase + (4 + i) * CSTRIDE + t * 32) =
                    cvt4(sj[i][0], sj[i][1], sj[i][2], sj[i][3]);
            }
        }
        __syncthreads();   // one barrier per layer: writes visible before next K
    }

    // ---------------- output: 112 rows x 256 dot Wout(f16); 2 threads/row ----------------
    // Final activations live in bufB (layer 2 wrote bufB).
    if (tid < 7 * MS * 2) {
        const int row = tid >> 1;        // 0..111
        const int h   = tid & 1;
        const _Float16* rp = &bufB[row * LDAK + h * 128];
        const _Float16* wq = Wq + h * 128;
        float accv = 0.f;
        #pragma unroll
        for (int kg = 0; kg < 16; ++kg) {
            fp16x8 av = *(const fp16x8*)&rp[kg * 8];
            fp16x8 wv = *(const fp16x8*)&wq[kg * 8];
#if __has_builtin(__builtin_amdgcn_fdot2)
            accv = __builtin_amdgcn_fdot2(__builtin_shufflevector(av, av, 0, 1),
                                          __builtin_shufflevector(wv, wv, 0, 1), accv, false);
            accv = __builtin_amdgcn_fdot2(__builtin_shufflevector(av, av, 2, 3),
                                          __builtin_shufflevector(wv, wv, 2, 3), accv, false);
            accv = __builtin_amdgcn_fdot2(__builtin_shufflevector(av, av, 4, 5),
                                          __builtin_shufflevector(wv, wv, 4, 5), accv, false);
            accv = __builtin_amdgcn_fdot2(__builtin_shufflevector(av, av, 6, 7),
                                          __builtin_shufflevector(wv, wv, 6, 7), accv, false);
#else
            #pragma unroll
            for (int j = 0; j < 8; ++j) accv += (float)av[j] * (float)wv[j];
#endif
        }
        accv += __shfl_xor(accv, 1, 64);
        if (h == 0) {
            const int c = row >> 4;
            const int m = row & 15;
            if (c == 0) accv += bout[0];
            out[(base + m) * 7 + c] = accv;
        }
    }
}

extern "C" void kernel_launch(void* const* d_in, const int* in_sizes, int n_in,
                              void* d_out, int out_size, void* d_ws, size_t ws_size,
                              hipStream_t stream) {
    const float* xp   = (const float*)d_in[0];
    const float* W0   = (const float*)d_in[1];
    const float* b0   = (const float*)d_in[2];
    const float* W1   = (const float*)d_in[3];
    const float* b1   = (const float*)d_in[4];
    const float* W2   = (const float*)d_in[5];
    const float* b2   = (const float*)d_in[6];
    const float* W3   = (const float*)d_in[7];
    const float* b3   = (const float*)d_in[8];
    const float* Wout = (const float*)d_in[9];
    const float* bout = (const float*)d_in[10];
    _Float16* Wp = (_Float16*)d_ws;            // 3*65536 + 256 halves
    const _Float16* Wq = Wp + 3 * 65536;       // f16 Wout

    hipFuncSetAttribute((const void*)pinn_fused,
                        hipFuncAttributeMaxDynamicSharedMemorySize, SMEM_BYTES);

    pack_weights<<<97, 256, 0, stream>>>(W1, W2, W3, Wout, Wp);
    pinn_fused<<<65536 / MS, 256, SMEM_BYTES, stream>>>(xp, W0, b0, b1, b2, b3,
                                                        Wq, bout, Wp,
                                                        (float*)d_out);
}

// Round 13
// 244.031 us; speedup vs baseline: 1.2110x; 1.2110x over previous
//
#include <hip/hip_runtime.h>
#include <hip/hip_fp16.h>

#define HDIM 256
#define MS 16
#define LDAK 264   // 256 + 8 halves pad; measured-balanced for b128 reads & b64 writes
#define CSTRIDE (MS * LDAK * 2)   // 8448 B per channel block

typedef _Float16 half8 __attribute__((ext_vector_type(8)));
typedef _Float16 half4 __attribute__((ext_vector_type(4)));
typedef _Float16 half2v __attribute__((ext_vector_type(2)));
typedef float f32x4 __attribute__((ext_vector_type(4)));

__device__ __forceinline__ float fast_tanh(float x) {
    // tanh(x) = 1 - 2/(e^{2x}+1); v_exp-based, graceful at +-inf
    float e = __expf(2.0f * x);
    return 1.0f - 2.0f * __builtin_amdgcn_rcpf(e + 1.0f);
}

__device__ __forceinline__ half4 cvt4(float a, float b, float c, float d) {
    half2v lo = __builtin_bit_cast(half2v, __builtin_amdgcn_cvt_pkrtz(a, b));
    half2v hi = __builtin_bit_cast(half2v, __builtin_amdgcn_cvt_pkrtz(c, d));
    half4 r; r[0] = lo[0]; r[1] = lo[1]; r[2] = hi[0]; r[3] = hi[1];
    return r;
}

// Workgroup barrier draining only LDS (lgkmcnt) — leaves in-flight global
// wf prefetches (vmcnt) pending across the barrier (AITER-style: never
// vmcnt(0) at a barrier). LDS writes before the barrier are visible after.
__device__ __forceinline__ void barrier_lds() {
    asm volatile("s_waitcnt lgkmcnt(0)\n\ts_barrier" ::: "memory");
}

// Pack W1,W2,W3 (fp32 [256][256]) into f16 frag layout Wp[g*8192 + frag], g = flat
// K-step l*8+s; within a step: kg-sub*2048 + n*8 + (k&7).
__global__ __launch_bounds__(256) void pack_weights(const float* __restrict__ W1,
                                                    const float* __restrict__ W2,
                                                    const float* __restrict__ W3,
                                                    _Float16* __restrict__ out) {
    int tid = blockIdx.x * 256 + threadIdx.x;  // 0..24575
    int l = tid >> 13;
    int idx = tid & 8191;   // kg*256 + n
    int kg = idx >> 8;      // k-group of 8
    int n = idx & 255;
    const float* W = (l == 0) ? W1 : (l == 1) ? W2 : W3;
    half8 v;
    #pragma unroll
    for (int j = 0; j < 8; ++j) v[j] = (_Float16)W[(kg * 8 + j) * 256 + n];
    *(half8*)(out + l * 65536 + kg * 2048 + n * 8) = v;
}

__global__ __launch_bounds__(256, 2)
void pinn_fused(const float* __restrict__ x,
                const float* __restrict__ W0,
                const float* __restrict__ b0,
                const float* __restrict__ b1,
                const float* __restrict__ b2,
                const float* __restrict__ b3,
                const float* __restrict__ Wout,
                const float* __restrict__ bout,
                const _Float16* __restrict__ Wp,
                float* __restrict__ out) {
    // A: stacked [7 channels x 16 samples] rows x 256 k, f16, pad-264
    __shared__ __align__(16) _Float16 Abuf[7 * MS][LDAK];
    __shared__ float part[4 * 7 * MS];   // per-wave output partials (1792 B)

    const int tid  = threadIdx.x;
    const int lane = tid & 63;
    const int wid  = tid >> 6;        // wave 0..3 -> n-strip base wid*64
    const int qd   = lane >> 4;
    const int n15  = lane & 15;
    const int base = blockIdx.x * MS;
    const int nw   = wid * 64 + n15;

    // Linear W addressing: frag(g,t) at Wp + g*8192 + voff0 + t*128 (halves).
    const int voff0 = (qd * 256 + nw) * 8;

    // 3-deep W pipeline over flat step g; g=0,1 issued before layer-0 math.
    half8 wf[3][4];
    #pragma unroll
    for (int t = 0; t < 4; ++t)
        wf[0][t] = *(const half8*)(Wp + 0 * 8192 + voff0 + t * 128);
    #pragma unroll
    for (int t = 0; t < 4; ++t)
        wf[1][t] = *(const half8*)(Wp + 1 * 8192 + voff0 + t * 128);

    // ---------------- layer 0: 3 -> 256, jets analytic; vectorized loads ----------------
    {
        const int m  = tid & 15;
        const int nb = (tid >> 4) * 16;   // 16 consecutive n per thread, 2 chunks
        const float x0 = x[(base + m) * 3 + 0];
        const float x1 = x[(base + m) * 3 + 1];
        const float x2 = x[(base + m) * 3 + 2];
        #pragma unroll
        for (int ch = 0; ch < 2; ++ch) {
            const int n0 = nb + ch * 8;
            f32x4 w0v[2], w1v[2], w2v[2], bv[2];
            w0v[0] = *(const f32x4*)(W0 + n0);            w0v[1] = *(const f32x4*)(W0 + n0 + 4);
            w1v[0] = *(const f32x4*)(W0 + HDIM + n0);     w1v[1] = *(const f32x4*)(W0 + HDIM + n0 + 4);
            w2v[0] = *(const f32x4*)(W0 + 2 * HDIM + n0); w2v[1] = *(const f32x4*)(W0 + 2 * HDIM + n0 + 4);
            bv[0]  = *(const f32x4*)(b0 + n0);            bv[1]  = *(const f32x4*)(b0 + n0 + 4);
            half8 h[7];
            #pragma unroll
            for (int r = 0; r < 8; ++r) {
                const float w0 = w0v[r >> 2][r & 3];
                const float w1 = w1v[r >> 2][r & 3];
                const float w2 = w2v[r >> 2][r & 3];
                float z  = x0 * w0 + x1 * w1 + x2 * w2 + bv[r >> 2][r & 3];
                float tv = fast_tanh(z);
                float dd = 1.f - tv * tv;
                float c2 = -2.f * tv * dd;
                h[0][r] = (_Float16)tv;
                h[1][r] = (_Float16)(dd * w0);
                h[2][r] = (_Float16)(dd * w1);
                h[3][r] = (_Float16)(dd * w2);
                h[4][r] = (_Float16)(c2 * w0 * w0);
                h[5][r] = (_Float16)(c2 * w1 * w1);
                h[6][r] = (_Float16)(c2 * w2 * w2);
            }
            #pragma unroll
            for (int c = 0; c < 7; ++c)
                *(half8*)&Abuf[c * MS + m][n0] = h[c];
        }
    }
    barrier_lds();

    // ---------------- layers 1..2: transposed MFMA + elem write-back ----------------
    const char* Ab = (const char*)Abuf;
    const int abase = (n15 * LDAK + qd * 8) * 2;                 // read base (bytes)
    char* Sb = (char*)Abuf;
    const int sbase = (n15 * LDAK + wid * 64 + qd * 4) * 2;      // write base (bytes)

    #pragma unroll
    for (int l = 0; l < 2; ++l) {
        const float* bb = (l == 0) ? b1 : b2;

        f32x4 acc[7][4];
        #pragma unroll
        for (int c = 0; c < 7; ++c)
            #pragma unroll
            for (int t = 0; t < 4; ++t) acc[c][t] = (f32x4){0.f, 0.f, 0.f, 0.f};

        #pragma unroll
        for (int s = 0; s < 8; ++s) {
            const int g = l * 8 + s;
            {   // prefetch step g+2's W frags (always valid for l<2: g+2 <= 17)
                #pragma unroll
                for (int t = 0; t < 4; ++t)
                    wf[(g + 2) % 3][t] =
                        *(const half8*)(Wp + (g + 2) * 8192 + voff0 + t * 128);
            }
            half8 af[7];
            #pragma unroll
            for (int c = 0; c < 7; ++c)
                af[c] = *(const half8*)(Ab + abase + c * CSTRIDE + s * 64);
            #pragma unroll
            for (int c = 0; c < 7; ++c)
                #pragma unroll
                for (int t = 0; t < 4; ++t)
                    acc[c][t] = __builtin_amdgcn_mfma_f32_16x16x32_f16(wf[g % 3][t], af[c], acc[c][t], 0, 0, 0);
        }
        barrier_lds();   // all waves done reading Abuf (lgkm only; wf stays in flight)

        // lane holds Z[m = n15][n = wid*64 + t*16 + qd*4 + r], r=0..3
        #pragma unroll
        for (int t = 0; t < 4; ++t) {
            const int ncol = wid * 64 + t * 16 + qd * 4;
            f32x4 bv = *(const f32x4*)(bb + ncol);
            float tv[4], gj[3][4], sj[3][4];
            #pragma unroll
            for (int r = 0; r < 4; ++r) {
                float zv = acc[0][t][r] + bv[r];
                tv[r] = fast_tanh(zv);
                float dd = 1.f - tv[r] * tv[r];
                float c2 = -2.f * tv[r] * dd;
                #pragma unroll
                for (int i = 0; i < 3; ++i) {
                    float zg = acc[1 + i][t][r];
                    float zs = acc[4 + i][t][r];
                    gj[i][r] = dd * zg;
                    sj[i][r] = dd * zs + c2 * zg * zg;
                }
            }
            *(half4*)(Sb + sbase + 0 * CSTRIDE + t * 32) = cvt4(tv[0], tv[1], tv[2], tv[3]);
            #pragma unroll
            for (int i = 0; i < 3; ++i) {
                *(half4*)(Sb + sbase + (1 + i) * CSTRIDE + t * 32) =
                    cvt4(gj[i][0], gj[i][1], gj[i][2], gj[i][3]);
                *(half4*)(Sb + sbase + (4 + i) * CSTRIDE + t * 32) =
                    cvt4(sj[i][0], sj[i][1], sj[i][2], sj[i][3]);
            }
        }
        barrier_lds();   // writes visible before next K
    }

    // ---------------- layer 3: K-loop + FUSED elem/output (no Abuf writes) ----------------
    {
        f32x4 acc[7][4];
        #pragma unroll
        for (int c = 0; c < 7; ++c)
            #pragma unroll
            for (int t = 0; t < 4; ++t) acc[c][t] = (f32x4){0.f, 0.f, 0.f, 0.f};

        #pragma unroll
        for (int s = 0; s < 8; ++s) {
            const int g = 16 + s;
            if (g + 2 < 24) {
                #pragma unroll
                for (int t = 0; t < 4; ++t)
                    wf[(g + 2) % 3][t] =
                        *(const half8*)(Wp + (g + 2) * 8192 + voff0 + t * 128);
            }
            half8 af[7];
            #pragma unroll
            for (int c = 0; c < 7; ++c)
                af[c] = *(const half8*)(Ab + abase + c * CSTRIDE + s * 64);
            #pragma unroll
            for (int c = 0; c < 7; ++c)
                #pragma unroll
                for (int t = 0; t < 4; ++t)
                    acc[c][t] = __builtin_amdgcn_mfma_f32_16x16x32_f16(wf[g % 3][t], af[c], acc[c][t], 0, 0, 0);
        }
        // No post-K barrier: fused elem touches only registers + `part`.

        // per-lane partial dot with Wout over this lane's 16 columns (fp32 path)
        float p[7] = {0.f, 0.f, 0.f, 0.f, 0.f, 0.f, 0.f};
        #pragma unroll
        for (int t = 0; t < 4; ++t) {
            const int ncol = wid * 64 + t * 16 + qd * 4;
            f32x4 bv = *(const f32x4*)(b3 + ncol);
            f32x4 wv = *(const f32x4*)(Wout + ncol);
            #pragma unroll
            for (int r = 0; r < 4; ++r) {
                float zv = acc[0][t][r] + bv[r];
                float tv = fast_tanh(zv);
                float dd = 1.f - tv * tv;
                float c2 = -2.f * tv * dd;
                p[0] += tv * wv[r];
                #pragma unroll
                for (int i = 0; i < 3; ++i) {
                    float zg = acc[1 + i][t][r];
                    float zs = acc[4 + i][t][r];
                    p[1 + i] += (dd * zg) * wv[r];
                    p[4 + i] += (dd * zs + c2 * zg * zg) * wv[r];
                }
            }
        }
        // reduce over the 4 qd lanes sharing sample n15
        #pragma unroll
        for (int c = 0; c < 7; ++c) {
            p[c] += __shfl_xor(p[c], 16, 64);
            p[c] += __shfl_xor(p[c], 32, 64);
        }
        if (lane < 16) {
            #pragma unroll
            for (int c = 0; c < 7; ++c)
                part[(wid * 7 + c) * MS + lane] = p[c];
        }
    }
    barrier_lds();

    // ---------------- final reduce across the 4 waves; store [B,7] ----------------
    if (tid < 7 * MS) {
        const int c = tid >> 4;   // channel
        const int m = tid & 15;   // sample
        float v = part[(0 * 7 + c) * MS + m] + part[(1 * 7 + c) * MS + m] +
                  part[(2 * 7 + c) * MS + m] + part[(3 * 7 + c) * MS + m];
        if (c == 0) v += bout[0];
        out[(base + m) * 7 + c] = v;
    }
}

extern "C" void kernel_launch(void* const* d_in, const int* in_sizes, int n_in,
                              void* d_out, int out_size, void* d_ws, size_t ws_size,
                              hipStream_t stream) {
    const float* xp   = (const float*)d_in[0];
    const float* W0   = (const float*)d_in[1];
    const float* b0   = (const float*)d_in[2];
    const float* W1   = (const float*)d_in[3];
    const float* b1   = (const float*)d_in[4];
    const float* W2   = (const float*)d_in[5];
    const float* b2   = (const float*)d_in[6];
    const float* W3   = (const float*)d_in[7];
    const float* b3   = (const float*)d_in[8];
    const float* Wout = (const float*)d_in[9];
    const float* bout = (const float*)d_in[10];
    _Float16* Wp = (_Float16*)d_ws;  // 3 * 65536 halves = 384 KB

    pack_weights<<<96, 256, 0, stream>>>(W1, W2, W3, Wp);
    pinn_fused<<<65536 / MS, 256, 0, stream>>>(xp, W0, b0, b1, b2, b3, Wout, bout, Wp,
                                               (float*)d_out);
}